// Round 7
// baseline (309.311 us; speedup 1.0000x reference)
//
#include <hip/hip_runtime.h>
#include <hip/hip_bf16.h>

#define B_    8
#define N_    2048
#define DIN_  512
#define DOUT_ 256
#define NBUCK 20

typedef __attribute__((ext_vector_type(8))) short  short8;
typedef __attribute__((ext_vector_type(4))) float  floatx4;

__device__ __forceinline__ unsigned short f2b(float f) {
    __hip_bfloat16 h = __float2bfloat16(f);
    unsigned short u;
    __builtin_memcpy(&u, &h, 2);
    return u;
}

// ---------------- wvs = Wv^T . Ws (512 floats), bvs = bv . Ws ----------------
__global__ __launch_bounds__(128) void wvs_kernel(const float* __restrict__ Wv,
                                                  const float* __restrict__ Ws,
                                                  const float* __restrict__ bv,
                                                  float* __restrict__ wvs,
                                                  float* __restrict__ bvs) {
    __shared__ float wsl[DOUT_];
    int tid = threadIdx.x;
    wsl[tid] = Ws[tid];
    wsl[tid + 128] = Ws[tid + 128];
    __syncthreads();
    int d = blockIdx.x * 128 + tid;
    float s = 0.f;
#pragma unroll 8
    for (int o = 0; o < DOUT_; ++o) s += Wv[(size_t)o * DIN_ + d] * wsl[o];
    wvs[d] = s;
    if (blockIdx.x == 0 && tid < 64) {
        float bb = wsl[tid] * bv[tid] + wsl[tid + 64] * bv[tid + 64] +
                   wsl[tid + 128] * bv[tid + 128] + wsl[tid + 192] * bv[tid + 192];
        for (int off = 1; off < 64; off <<= 1) bb += __shfl_xor(bb, off, 64);
        if (tid == 0) *bvs = bb;
    }
}

// ---------------- x -> bf16, fused vw = x . wvs + bvs ----------------
__global__ __launch_bounds__(256) void cvt_x_kernel(const float* __restrict__ x,
                                                    const float* __restrict__ wvs,
                                                    const float* __restrict__ bvs,
                                                    unsigned short* __restrict__ xb,
                                                    float* __restrict__ vw) {
    int tid = threadIdx.x, wave = tid >> 6, lane = tid & 63;
    int row = blockIdx.x * 4 + wave;
    size_t base = (size_t)row * DIN_ + lane * 8;
    float4 a = *(const float4*)(x + base);
    float4 b = *(const float4*)(x + base + 4);
    float4 wa = *(const float4*)(wvs + lane * 8);
    float4 wb = *(const float4*)(wvs + lane * 8 + 4);
    uint4 r;
    r.x = f2b(a.x) | ((unsigned)f2b(a.y) << 16);
    r.y = f2b(a.z) | ((unsigned)f2b(a.w) << 16);
    r.z = f2b(b.x) | ((unsigned)f2b(b.y) << 16);
    r.w = f2b(b.z) | ((unsigned)f2b(b.w) << 16);
    *(uint4*)(xb + base) = r;
    float d = a.x * wa.x + a.y * wa.y + a.z * wa.z + a.w * wa.w +
              b.x * wb.x + b.y * wb.y + b.z * wb.z + b.w * wb.w;
    for (int off = 1; off < 64; off <<= 1) d += __shfl_xor(d, off, 64);
    if (lane == 0) vw[row] = d + *bvs;
}

// ---------------- Wq,Wk -> bf16 ----------------
__global__ __launch_bounds__(256) void cvt_w_kernel(const float* __restrict__ wq,
                                                    const float* __restrict__ wk,
                                                    unsigned short* __restrict__ dst) {
    int i = (blockIdx.x * 256 + threadIdx.x) * 8;  // 0 .. 262144-8
    const float* src = (i < 131072) ? (wq + i) : (wk + (i - 131072));
    float4 a = *(const float4*)(src);
    float4 b = *(const float4*)(src + 4);
    uint4 r;
    r.x = f2b(a.x) | ((unsigned)f2b(a.y) << 16);
    r.y = f2b(a.z) | ((unsigned)f2b(a.w) << 16);
    r.z = f2b(b.x) | ((unsigned)f2b(b.y) << 16);
    r.w = f2b(b.z) | ((unsigned)f2b(b.w) << 16);
    *(uint4*)(dst + i) = r;
}

// ---------------- Q,K GEMM ----------------
// grid (256, 8): x = 64-row block (16 rows/wave), y = 64-col block of 512 outputs.
// 2048 blocks = 8/CU; lean registers (acc[4] only) for max TLP — attacking the
// latency-bound profile with wave count rather than per-wave unrolling
// (full unroll spills: round-5 lesson).
__global__ __launch_bounds__(256, 8) void qkv_kernel(
    const unsigned short* __restrict__ xb, const unsigned short* __restrict__ wb,
    const float* __restrict__ bq, const float* __restrict__ bk,
    unsigned short* __restrict__ q, unsigned short* __restrict__ k) {
    const int tid  = threadIdx.x;
    const int wave = tid >> 6, lane = tid & 63, quad = lane >> 4, l16 = lane & 15;
    const int row0 = blockIdx.x * 64 + wave * 16;
    const int col0 = blockIdx.y * 64;

    floatx4 acc[4];
#pragma unroll
    for (int t = 0; t < 4; ++t) acc[t] = (floatx4){0.f, 0.f, 0.f, 0.f};

    const unsigned short* arow = xb + (size_t)(row0 + l16) * DIN_ + quad * 8;
    const unsigned short* brow = wb + (size_t)(col0 + l16) * DIN_ + quad * 8;
#pragma unroll 2
    for (int kc = 0; kc < DIN_; kc += 32) {
        short8 af = *(const short8*)(arow + kc);
#pragma unroll
        for (int ct = 0; ct < 4; ++ct) {
            short8 bf = *(const short8*)(brow + (size_t)ct * 16 * DIN_ + kc);
            acc[ct] = __builtin_amdgcn_mfma_f32_16x16x32_bf16(af, bf, acc[ct], 0, 0, 0);
        }
    }
#pragma unroll
    for (int ct = 0; ct < 4; ++ct) {
        int col = col0 + ct * 16 + l16;
        unsigned short* dst = (col < 256) ? q : k;
        float bias = (col < 256) ? bq[col] : bk[col - 256];
        int c = col & 255;
#pragma unroll
        for (int r = 0; r < 4; ++r) {
            int row = row0 + quad * 4 + r;
            dst[(size_t)row * DOUT_ + c] = f2b(acc[ct][r] + bias);
        }
    }
}

// ---------------- gated flash attention, scalarized V path ----------------
// grid 1024: b = g&7 (XCD-affine: all blocks of batch b share an XCD so K
// stays L2-hot), rblk = g>>3 -> 16 q-rows. 512 threads = 8 waves = 8 m-splits
// of 256 columns (8 iters of 32). All splits combine inside the block via LDS
// (no cross-workgroup traffic — round-6 coherence lesson). pr/vw prefetched
// to registers; unroll 1 pinned (full unroll spills — round-5 lesson).
// Occupancy: 4 blocks/CU x 8 waves, VGPR-capped ~5 waves/SIMD.
__global__ __launch_bounds__(512, 4) void attn_kernel(
    const unsigned short* __restrict__ q, const unsigned short* __restrict__ k,
    const float* __restrict__ vw, const int* __restrict__ pr,
    const float* __restrict__ rank_emb, const float* __restrict__ rank_w,
    const float* __restrict__ bs, const float* __restrict__ bvs,
    float* __restrict__ out) {
    const int g = blockIdx.x;
    const int b = g & 7, rblk = g >> 3;
    const int tid = threadIdx.x, wave = tid >> 6, lane = tid & 63;
    const int quad = lane >> 4, l16 = lane & 15;
    const int sp = wave;            // m split 0..7
    const int n0 = rblk * 16;
    const int mbeg = sp * 256;

    __shared__ float gtab[NBUCK];
    __shared__ float lL[8][16], wdL[8][16];

    if (tid < NBUCK)  // scale * log2e folded in
        gtab[tid] = 0.0625f * 1.44269504f / (1.f + __expf(-rank_w[0] * rank_emb[tid]));
    __syncthreads();

    const unsigned short* qb = q + (size_t)b * N_ * DOUT_;
    const unsigned short* kb = k + (size_t)b * N_ * DOUT_;
    const float* vwb = vw + b * N_;
    const int* prb = pr + b * N_;

    short8 qf[8];
#pragma unroll
    for (int c = 0; c < 8; ++c)
        qf[c] = *(const short8*)(qb + (size_t)(n0 + l16) * DOUT_ + c * 32 + quad * 8);

    float prn[4];
#pragma unroll
    for (int r = 0; r < 4; ++r) prn[r] = (float)prb[n0 + quad * 4 + r];

    // prefetch pr/vw for this wave's 256 columns (16 x 16-col groups)
    float prw[16], vww[16];
#pragma unroll
    for (int j = 0; j < 16; ++j) {
        int col = mbeg + j * 16 + l16;
        prw[j] = (float)prb[col];
        vww[j] = vwb[col];
    }

    float lacc[4], wacc[4];
#pragma unroll
    for (int r = 0; r < 4; ++r) { lacc[r] = 0.f; wacc[r] = 0.f; }

#pragma unroll 1
    for (int mi = 0; mi < 8; ++mi) {
        const int m0 = mbeg + mi * 32;
        floatx4 s[2];
        s[0] = (floatx4){0.f, 0.f, 0.f, 0.f};
        s[1] = (floatx4){0.f, 0.f, 0.f, 0.f};
#pragma unroll
        for (int h = 0; h < 2; ++h) {
            const unsigned short* krow = kb + (size_t)(m0 + h * 16 + l16) * DOUT_ + quad * 8;
#pragma unroll
            for (int c = 0; c < 8; ++c) {
                short8 kf = *(const short8*)(krow + c * 32);
                s[h] = __builtin_amdgcn_mfma_f32_16x16x32_bf16(qf[c], kf, s[h], 0, 0, 0);
            }
        }
#pragma unroll
        for (int h = 0; h < 2; ++h) {
            float prm = prw[mi * 2 + h];
            float vwv = vww[mi * 2 + h];
#pragma unroll
            for (int r = 0; r < 4; ++r) {
                float d5 = fabsf(prn[r] - prm) * 0.2f;
                int idx = (int)fminf(d5, 19.0f);
                float p = exp2f(s[h][r] * gtab[idx]);
                lacc[r] += p;
                wacc[r] += p * vwv;
            }
        }
    }

    // merge partial (l, wd) across the 16 column-lanes
#pragma unroll
    for (int off = 1; off < 16; off <<= 1) {
#pragma unroll
        for (int r = 0; r < 4; ++r) {
            lacc[r] += __shfl_xor(lacc[r], off, 64);
            wacc[r] += __shfl_xor(wacc[r], off, 64);
        }
    }
    if (l16 == 0) {
#pragma unroll
        for (int r = 0; r < 4; ++r) {
            int row = quad * 4 + r;
            lL[sp][row]  = lacc[r];
            wdL[sp][row] = wacc[r];
        }
    }
    __syncthreads();
    if (tid < 16) {
        float l = 0.f, wd = 0.f;
#pragma unroll
        for (int s2 = 0; s2 < 8; ++s2) { l += lL[s2][tid]; wd += wdL[s2][tid]; }
        float logit = wd / l + *bvs + bs[0];
        out[(size_t)b * N_ + n0 + tid] = 1.f / (1.f + __expf(-logit));
    }
}

// ---------------- launch ----------------
extern "C" void kernel_launch(void* const* d_in, const int* in_sizes, int n_in,
                              void* d_out, int out_size, void* d_ws, size_t ws_size,
                              hipStream_t stream) {
    const float* x   = (const float*)d_in[0];
    const int*   pr  = (const int*)d_in[1];
    const float* Wq  = (const float*)d_in[2];
    const float* bq  = (const float*)d_in[3];
    const float* Wk  = (const float*)d_in[4];
    const float* bk  = (const float*)d_in[5];
    const float* Wv  = (const float*)d_in[6];
    const float* bv  = (const float*)d_in[7];
    const float* Ws  = (const float*)d_in[8];
    const float* bs  = (const float*)d_in[9];
    const float* remb = (const float*)d_in[10];
    const float* rw   = (const float*)d_in[11];
    float* out = (float*)d_out;

    char* ws = (char*)d_ws;
    unsigned short* xb  = (unsigned short*)ws;                    // 16,777,216 B
    unsigned short* wb  = (unsigned short*)(ws + 16777216);       //    524,288 B
    unsigned short* q   = (unsigned short*)(ws + 17301504);       //  8,388,608 B
    unsigned short* kk  = (unsigned short*)(ws + 25690112);       //  8,388,608 B
    float*          vwp = (float*)(ws + 34078720);                //     65,536 B
    float*          wvs = (float*)(ws + 34144256);                //      2,048 B
    float*          bvs = (float*)(ws + 34146304);                //          4 B

    hipLaunchKernelGGL(wvs_kernel, dim3(4), dim3(128), 0, stream, Wv, Ws, bv, wvs, bvs);
    hipLaunchKernelGGL(cvt_x_kernel, dim3(4096), dim3(256), 0, stream, x, wvs, bvs, xb, vwp);
    hipLaunchKernelGGL(cvt_w_kernel, dim3(128), dim3(256), 0, stream, Wq, Wk, wb);
    hipLaunchKernelGGL(qkv_kernel, dim3(256, 8), dim3(256), 0, stream,
                       xb, wb, bq, bk, q, kk);
    hipLaunchKernelGGL(attn_kernel, dim3(1024), dim3(512), 0, stream,
                       q, kk, vwp, pr, remb, rw, bs, bvs, out);
}

// Round 8
// 226.698 us; speedup vs baseline: 1.3644x; 1.3644x over previous
//
#include <hip/hip_runtime.h>
#include <hip/hip_bf16.h>

#define B_    8
#define N_    2048
#define DIN_  512
#define DOUT_ 256
#define NBUCK 20

typedef __attribute__((ext_vector_type(8))) short  short8;
typedef __attribute__((ext_vector_type(4))) float  floatx4;

__device__ __forceinline__ unsigned short f2b(float f) {
    __hip_bfloat16 h = __float2bfloat16(f);
    unsigned short u;
    __builtin_memcpy(&u, &h, 2);
    return u;
}

// ---------------- wvs = Wv^T . Ws (512 floats), bvs = bv . Ws ----------------
__global__ __launch_bounds__(128) void wvs_kernel(const float* __restrict__ Wv,
                                                  const float* __restrict__ Ws,
                                                  const float* __restrict__ bv,
                                                  float* __restrict__ wvs,
                                                  float* __restrict__ bvs) {
    __shared__ float wsl[DOUT_];
    int tid = threadIdx.x;
    wsl[tid] = Ws[tid];
    wsl[tid + 128] = Ws[tid + 128];
    __syncthreads();
    int d = blockIdx.x * 128 + tid;
    float s = 0.f;
#pragma unroll 8
    for (int o = 0; o < DOUT_; ++o) s += Wv[(size_t)o * DIN_ + d] * wsl[o];
    wvs[d] = s;
    if (blockIdx.x == 0 && tid < 64) {
        float bb = wsl[tid] * bv[tid] + wsl[tid + 64] * bv[tid + 64] +
                   wsl[tid + 128] * bv[tid + 128] + wsl[tid + 192] * bv[tid + 192];
        for (int off = 1; off < 64; off <<= 1) bb += __shfl_xor(bb, off, 64);
        if (tid == 0) *bvs = bb;
    }
}

// ---------------- x -> bf16, fused vw = x . wvs + bvs ----------------
__global__ __launch_bounds__(256) void cvt_x_kernel(const float* __restrict__ x,
                                                    const float* __restrict__ wvs,
                                                    const float* __restrict__ bvs,
                                                    unsigned short* __restrict__ xb,
                                                    float* __restrict__ vw) {
    int tid = threadIdx.x, wave = tid >> 6, lane = tid & 63;
    int row = blockIdx.x * 4 + wave;
    size_t base = (size_t)row * DIN_ + lane * 8;
    float4 a = *(const float4*)(x + base);
    float4 b = *(const float4*)(x + base + 4);
    float4 wa = *(const float4*)(wvs + lane * 8);
    float4 wb = *(const float4*)(wvs + lane * 8 + 4);
    uint4 r;
    r.x = f2b(a.x) | ((unsigned)f2b(a.y) << 16);
    r.y = f2b(a.z) | ((unsigned)f2b(a.w) << 16);
    r.z = f2b(b.x) | ((unsigned)f2b(b.y) << 16);
    r.w = f2b(b.z) | ((unsigned)f2b(b.w) << 16);
    *(uint4*)(xb + base) = r;
    float d = a.x * wa.x + a.y * wa.y + a.z * wa.z + a.w * wa.w +
              b.x * wb.x + b.y * wb.y + b.z * wb.z + b.w * wb.w;
    for (int off = 1; off < 64; off <<= 1) d += __shfl_xor(d, off, 64);
    if (lane == 0) vw[row] = d + *bvs;
}

// ---------------- Wq,Wk -> bf16 ----------------
__global__ __launch_bounds__(256) void cvt_w_kernel(const float* __restrict__ wq,
                                                    const float* __restrict__ wk,
                                                    unsigned short* __restrict__ dst) {
    int i = (blockIdx.x * 256 + threadIdx.x) * 8;  // 0 .. 262144-8
    const float* src = (i < 131072) ? (wq + i) : (wk + (i - 131072));
    float4 a = *(const float4*)(src);
    float4 b = *(const float4*)(src + 4);
    uint4 r;
    r.x = f2b(a.x) | ((unsigned)f2b(a.y) << 16);
    r.y = f2b(a.z) | ((unsigned)f2b(a.w) << 16);
    r.z = f2b(b.x) | ((unsigned)f2b(b.y) << 16);
    r.w = f2b(b.z) | ((unsigned)f2b(b.w) << 16);
    *(uint4*)(dst + i) = r;
}

// ---------------- Q,K GEMM ----------------
// grid 1024 flattened, XCD-affinity swizzle: xcd = g&7, colBlk = (g>>3)&7,
// rowGrp = g>>6 -> rowBlk = rowGrp*8 + xcd. All 8 col-blocks sharing a
// 128-row A stripe land on the SAME XCD (consecutive blockIdx round-robin
// over XCDs), so A rows are read once from L3 and 7x from L2 (2 MB/XCD),
// and each XCD's B working set (512 KB) stays L2-hot.
// 32 rows/wave (each B fragment feeds 2 MFMAs — round-7 lesson: operand
// reuse beats wave count). unroll 2 only (full unroll spills — round-5).
__global__ __launch_bounds__(256, 4) void qkv_kernel(
    const unsigned short* __restrict__ xb, const unsigned short* __restrict__ wb,
    const float* __restrict__ bq, const float* __restrict__ bk,
    unsigned short* __restrict__ q, unsigned short* __restrict__ k) {
    const int g = blockIdx.x;
    const int xcd = g & 7, colBlk = (g >> 3) & 7, rowGrp = g >> 6;
    const int rowBlk = rowGrp * 8 + xcd;
    const int tid  = threadIdx.x;
    const int wave = tid >> 6, lane = tid & 63, quad = lane >> 4, l16 = lane & 15;
    const int row0 = rowBlk * 128 + wave * 32;
    const int col0 = colBlk * 64;

    floatx4 acc[2][4];
#pragma unroll
    for (int a = 0; a < 2; ++a)
#pragma unroll
        for (int t = 0; t < 4; ++t) acc[a][t] = (floatx4){0.f, 0.f, 0.f, 0.f};

    const unsigned short* arow0 = xb + (size_t)(row0 + l16) * DIN_ + quad * 8;
    const unsigned short* arow1 = xb + (size_t)(row0 + 16 + l16) * DIN_ + quad * 8;
    const unsigned short* brow  = wb + (size_t)(col0 + l16) * DIN_ + quad * 8;
#pragma unroll 2
    for (int kc = 0; kc < DIN_; kc += 32) {
        short8 af0 = *(const short8*)(arow0 + kc);
        short8 af1 = *(const short8*)(arow1 + kc);
#pragma unroll
        for (int ct = 0; ct < 4; ++ct) {
            short8 bf = *(const short8*)(brow + (size_t)ct * 16 * DIN_ + kc);
            acc[0][ct] = __builtin_amdgcn_mfma_f32_16x16x32_bf16(af0, bf, acc[0][ct], 0, 0, 0);
            acc[1][ct] = __builtin_amdgcn_mfma_f32_16x16x32_bf16(af1, bf, acc[1][ct], 0, 0, 0);
        }
    }
#pragma unroll
    for (int ct = 0; ct < 4; ++ct) {
        int col = col0 + ct * 16 + l16;
        unsigned short* dst = (col < 256) ? q : k;
        float bias = (col < 256) ? bq[col] : bk[col - 256];
        int c = col & 255;
#pragma unroll
        for (int a = 0; a < 2; ++a)
#pragma unroll
            for (int r = 0; r < 4; ++r) {
                int row = row0 + a * 16 + quad * 4 + r;
                dst[(size_t)row * DOUT_ + c] = f2b(acc[a][ct][r] + bias);
            }
    }
}

// ---------------- gated flash attention, scalarized V path ----------------
// grid 512: b = g&7 (XCD-affine: batch's K stays L2-hot), rblk = g>>3 ->
// 32 q-rows. 512 threads = 8 waves = 8 m-splits of 256 columns; all waves
// share the same 32 q-rows (each K fragment feeds 2 MFMAs). Per-lane
// fixed-max softmax accumulation; float-math gate bucket (ranks < 2048 are
// exact in fp32; k*5*0.2f rounds to exactly k). Exact round-4 structure —
// best measured (80 us) — no prefetch arrays (register pressure: r5 lesson).
__global__ __launch_bounds__(512, 4) void attn_kernel(
    const unsigned short* __restrict__ q, const unsigned short* __restrict__ k,
    const float* __restrict__ vw, const int* __restrict__ pr,
    const float* __restrict__ rank_emb, const float* __restrict__ rank_w,
    const float* __restrict__ bs, const float* __restrict__ bvs,
    float* __restrict__ out) {
    const int g = blockIdx.x;
    const int b = g & 7, rblk = g >> 3;
    const int tid = threadIdx.x, wave = tid >> 6, lane = tid & 63;
    const int quad = lane >> 4, l16 = lane & 15;
    const int sp = wave;            // m split 0..7
    const int n0 = rblk * 32;

    __shared__ float gtab[NBUCK];
    __shared__ float lL[8][32], wdL[8][32];

    if (tid < NBUCK)  // scale * log2e folded in
        gtab[tid] = 0.0625f * 1.44269504f / (1.f + __expf(-rank_w[0] * rank_emb[tid]));
    __syncthreads();

    const unsigned short* qb = q + (size_t)b * N_ * DOUT_;
    const unsigned short* kb = k + (size_t)b * N_ * DOUT_;
    const float* vwb = vw + b * N_;
    const int* prb = pr + b * N_;

    short8 qf[2][8];
#pragma unroll
    for (int a = 0; a < 2; ++a)
#pragma unroll
        for (int c = 0; c < 8; ++c)
            qf[a][c] = *(const short8*)(qb + (size_t)(n0 + a * 16 + l16) * DOUT_ + c * 32 + quad * 8);

    float prn[2][4];
#pragma unroll
    for (int a = 0; a < 2; ++a)
#pragma unroll
        for (int r = 0; r < 4; ++r) prn[a][r] = (float)prb[n0 + a * 16 + quad * 4 + r];

    float lacc[2][4], wacc[2][4];
#pragma unroll
    for (int a = 0; a < 2; ++a)
#pragma unroll
        for (int r = 0; r < 4; ++r) { lacc[a][r] = 0.f; wacc[a][r] = 0.f; }

    const int mbeg = sp * 256;
#pragma unroll 1
    for (int mi = 0; mi < 8; ++mi) {
        const int m0 = mbeg + mi * 32;
        floatx4 s[2][2];
#pragma unroll
        for (int a = 0; a < 2; ++a)
#pragma unroll
            for (int h = 0; h < 2; ++h) s[a][h] = (floatx4){0.f, 0.f, 0.f, 0.f};
#pragma unroll
        for (int h = 0; h < 2; ++h) {
            const unsigned short* krow = kb + (size_t)(m0 + h * 16 + l16) * DOUT_ + quad * 8;
#pragma unroll
            for (int c = 0; c < 8; ++c) {
                short8 kf = *(const short8*)(krow + c * 32);
                s[0][h] = __builtin_amdgcn_mfma_f32_16x16x32_bf16(qf[0][c], kf, s[0][h], 0, 0, 0);
                s[1][h] = __builtin_amdgcn_mfma_f32_16x16x32_bf16(qf[1][c], kf, s[1][h], 0, 0, 0);
            }
        }
#pragma unroll
        for (int h = 0; h < 2; ++h) {
            int col = m0 + h * 16 + l16;
            float prm = (float)prb[col];
            float vwv = vwb[col];
#pragma unroll
            for (int a = 0; a < 2; ++a)
#pragma unroll
                for (int r = 0; r < 4; ++r) {
                    float d5 = fabsf(prn[a][r] - prm) * 0.2f;
                    int idx = (int)fminf(d5, 19.0f);
                    float p = exp2f(s[a][h][r] * gtab[idx]);
                    lacc[a][r] += p;
                    wacc[a][r] += p * vwv;
                }
        }
    }

    // merge partial (l, wd) across the 16 column-lanes
#pragma unroll
    for (int off = 1; off < 16; off <<= 1) {
#pragma unroll
        for (int a = 0; a < 2; ++a)
#pragma unroll
            for (int r = 0; r < 4; ++r) {
                lacc[a][r] += __shfl_xor(lacc[a][r], off, 64);
                wacc[a][r] += __shfl_xor(wacc[a][r], off, 64);
            }
    }
    if (l16 == 0) {
#pragma unroll
        for (int a = 0; a < 2; ++a)
#pragma unroll
            for (int r = 0; r < 4; ++r) {
                int row = a * 16 + quad * 4 + r;
                lL[sp][row]  = lacc[a][r];
                wdL[sp][row] = wacc[a][r];
            }
    }
    __syncthreads();
    if (tid < 32) {
        float l = 0.f, wd = 0.f;
#pragma unroll
        for (int s2 = 0; s2 < 8; ++s2) { l += lL[s2][tid]; wd += wdL[s2][tid]; }
        float logit = wd / l + *bvs + bs[0];
        out[(size_t)b * N_ + n0 + tid] = 1.f / (1.f + __expf(-logit));
    }
}

// ---------------- launch ----------------
extern "C" void kernel_launch(void* const* d_in, const int* in_sizes, int n_in,
                              void* d_out, int out_size, void* d_ws, size_t ws_size,
                              hipStream_t stream) {
    const float* x   = (const float*)d_in[0];
    const int*   pr  = (const int*)d_in[1];
    const float* Wq  = (const float*)d_in[2];
    const float* bq  = (const float*)d_in[3];
    const float* Wk  = (const float*)d_in[4];
    const float* bk  = (const float*)d_in[5];
    const float* Wv  = (const float*)d_in[6];
    const float* bv  = (const float*)d_in[7];
    const float* Ws  = (const float*)d_in[8];
    const float* bs  = (const float*)d_in[9];
    const float* remb = (const float*)d_in[10];
    const float* rw   = (const float*)d_in[11];
    float* out = (float*)d_out;

    char* ws = (char*)d_ws;
    unsigned short* xb  = (unsigned short*)ws;                    // 16,777,216 B
    unsigned short* wb  = (unsigned short*)(ws + 16777216);       //    524,288 B
    unsigned short* q   = (unsigned short*)(ws + 17301504);       //  8,388,608 B
    unsigned short* kk  = (unsigned short*)(ws + 25690112);       //  8,388,608 B
    float*          vwp = (float*)(ws + 34078720);                //     65,536 B
    float*          wvs = (float*)(ws + 34144256);                //      2,048 B
    float*          bvs = (float*)(ws + 34146304);                //          4 B

    hipLaunchKernelGGL(wvs_kernel, dim3(4), dim3(128), 0, stream, Wv, Ws, bv, wvs, bvs);
    hipLaunchKernelGGL(cvt_x_kernel, dim3(4096), dim3(256), 0, stream, x, wvs, bvs, xb, vwp);
    hipLaunchKernelGGL(cvt_w_kernel, dim3(128), dim3(256), 0, stream, Wq, Wk, wb);
    hipLaunchKernelGGL(qkv_kernel, dim3(1024), dim3(256), 0, stream,
                       xb, wb, bq, bk, q, kk);
    hipLaunchKernelGGL(attn_kernel, dim3(512), dim3(512), 0, stream,
                       q, kk, vwp, pr, remb, rw, bs, bvs, out);
}

// Round 9
// 212.318 us; speedup vs baseline: 1.4568x; 1.0677x over previous
//
#include <hip/hip_runtime.h>
#include <hip/hip_bf16.h>

#define B_    8
#define N_    2048
#define DIN_  512
#define DOUT_ 256
#define NBUCK 20

typedef __attribute__((ext_vector_type(8))) short  short8;
typedef __attribute__((ext_vector_type(4))) float  floatx4;

__device__ __forceinline__ unsigned short f2b(float f) {
    __hip_bfloat16 h = __float2bfloat16(f);
    unsigned short u;
    __builtin_memcpy(&u, &h, 2);
    return u;
}

__device__ __forceinline__ void load_lds16(const unsigned short* g, unsigned short* l) {
    __builtin_amdgcn_global_load_lds(
        (const __attribute__((address_space(1))) unsigned int*)g,
        (__attribute__((address_space(3))) unsigned int*)l, 16, 0, 0);
}

// ---------------- fused prep: Wq,Wk -> bf16  +  wvs = Wv^T.Ws, bvs = bv.Ws ----
// blocks 0..127: convert Wq|Wk. blocks 128..131: wvs/bvs.
__global__ __launch_bounds__(256) void prep_kernel(
    const float* __restrict__ wq, const float* __restrict__ wk,
    const float* __restrict__ Wv, const float* __restrict__ Ws,
    const float* __restrict__ bv,
    unsigned short* __restrict__ dst, float* __restrict__ wvs,
    float* __restrict__ bvs) {
    const int blk = blockIdx.x, tid = threadIdx.x;
    if (blk < 128) {
        int i = (blk * 256 + tid) * 8;  // 0 .. 262144-8
        const float* src = (i < 131072) ? (wq + i) : (wk + (i - 131072));
        float4 a = *(const float4*)(src);
        float4 b = *(const float4*)(src + 4);
        uint4 r;
        r.x = f2b(a.x) | ((unsigned)f2b(a.y) << 16);
        r.y = f2b(a.z) | ((unsigned)f2b(a.w) << 16);
        r.z = f2b(b.x) | ((unsigned)f2b(b.y) << 16);
        r.w = f2b(b.z) | ((unsigned)f2b(b.w) << 16);
        *(uint4*)(dst + i) = r;
    } else {
        __shared__ float wsl[DOUT_];
        wsl[tid] = Ws[tid];
        __syncthreads();
        if (tid < 128) {
            int d = (blk - 128) * 128 + tid;
            float s = 0.f;
#pragma unroll 8
            for (int o = 0; o < DOUT_; ++o) s += Wv[(size_t)o * DIN_ + d] * wsl[o];
            wvs[d] = s;
        }
        if (blk == 128 && tid < 64) {
            float bb = wsl[tid] * bv[tid] + wsl[tid + 64] * bv[tid + 64] +
                       wsl[tid + 128] * bv[tid + 128] + wsl[tid + 192] * bv[tid + 192];
            for (int off = 1; off < 64; off <<= 1) bb += __shfl_xor(bb, off, 64);
            if (tid == 0) *bvs = bb;
        }
    }
}

// ---------------- x -> bf16, fused vw = x . wvs + bvs ----------------
__global__ __launch_bounds__(256) void cvt_x_kernel(const float* __restrict__ x,
                                                    const float* __restrict__ wvs,
                                                    const float* __restrict__ bvs,
                                                    unsigned short* __restrict__ xb,
                                                    float* __restrict__ vw) {
    int tid = threadIdx.x, wave = tid >> 6, lane = tid & 63;
    int row = blockIdx.x * 4 + wave;
    size_t base = (size_t)row * DIN_ + lane * 8;
    float4 a = *(const float4*)(x + base);
    float4 b = *(const float4*)(x + base + 4);
    float4 wa = *(const float4*)(wvs + lane * 8);
    float4 wb = *(const float4*)(wvs + lane * 8 + 4);
    uint4 r;
    r.x = f2b(a.x) | ((unsigned)f2b(a.y) << 16);
    r.y = f2b(a.z) | ((unsigned)f2b(a.w) << 16);
    r.z = f2b(b.x) | ((unsigned)f2b(b.y) << 16);
    r.w = f2b(b.z) | ((unsigned)f2b(b.w) << 16);
    *(uint4*)(xb + base) = r;
    float d = a.x * wa.x + a.y * wa.y + a.z * wa.z + a.w * wa.w +
              b.x * wb.x + b.y * wb.y + b.z * wb.z + b.w * wb.w;
    for (int off = 1; off < 64; off <<= 1) d += __shfl_xor(d, off, 64);
    if (lane == 0) vw[row] = d + *bvs;  // bvs folded in HERE (only here)
}

// ---------------- Q,K GEMM (unchanged from round 8) ----------------
__global__ __launch_bounds__(256, 4) void qkv_kernel(
    const unsigned short* __restrict__ xb, const unsigned short* __restrict__ wb,
    const float* __restrict__ bq, const float* __restrict__ bk,
    unsigned short* __restrict__ q, unsigned short* __restrict__ k) {
    const int g = blockIdx.x;
    const int xcd = g & 7, colBlk = (g >> 3) & 7, rowGrp = g >> 6;
    const int rowBlk = rowGrp * 8 + xcd;
    const int tid  = threadIdx.x;
    const int wave = tid >> 6, lane = tid & 63, quad = lane >> 4, l16 = lane & 15;
    const int row0 = rowBlk * 128 + wave * 32;
    const int col0 = colBlk * 64;

    floatx4 acc[2][4];
#pragma unroll
    for (int a = 0; a < 2; ++a)
#pragma unroll
        for (int t = 0; t < 4; ++t) acc[a][t] = (floatx4){0.f, 0.f, 0.f, 0.f};

    const unsigned short* arow0 = xb + (size_t)(row0 + l16) * DIN_ + quad * 8;
    const unsigned short* arow1 = xb + (size_t)(row0 + 16 + l16) * DIN_ + quad * 8;
    const unsigned short* brow  = wb + (size_t)(col0 + l16) * DIN_ + quad * 8;
#pragma unroll 2
    for (int kc = 0; kc < DIN_; kc += 32) {
        short8 af0 = *(const short8*)(arow0 + kc);
        short8 af1 = *(const short8*)(arow1 + kc);
#pragma unroll
        for (int ct = 0; ct < 4; ++ct) {
            short8 bf = *(const short8*)(brow + (size_t)ct * 16 * DIN_ + kc);
            acc[0][ct] = __builtin_amdgcn_mfma_f32_16x16x32_bf16(af0, bf, acc[0][ct], 0, 0, 0);
            acc[1][ct] = __builtin_amdgcn_mfma_f32_16x16x32_bf16(af1, bf, acc[1][ct], 0, 0, 0);
        }
    }
#pragma unroll
    for (int ct = 0; ct < 4; ++ct) {
        int col = col0 + ct * 16 + l16;
        unsigned short* dst = (col < 256) ? q : k;
        float bias = (col < 256) ? bq[col] : bk[col - 256];
        int c = col & 255;
#pragma unroll
        for (int a = 0; a < 2; ++a)
#pragma unroll
            for (int r = 0; r < 4; ++r) {
                int row = row0 + a * 16 + quad * 4 + r;
                dst[(size_t)row * DOUT_ + c] = f2b(acc[a][ct][r] + bias);
            }
    }
}

// ---------------- gated flash attention, LDS-staged K (m97 pattern) ----------
// grid 512: b = g&7 (XCD-affine), rblk = g>>3 -> 32 q-rows, 8 waves.
// 16 chunks of 128 cols: stage K[chunk][256] (64 KB) via global_load_lds w16
// (async DMA, no VGPR round trip — r8's exposed per-lane VMEM chain was the
// stall), XOR-swizzle seg^=(row&7) applied to the GLOBAL source address so
// the LDS stays lane-contiguous (m104) while ds_read_b128 fragment reads
// spread across banks (residual 2-way = free). Each wave owns a 16-col slice
// per chunk: 8 ds_read_b128 + 16 MFMA + 8-elem exp. Two barriers per chunk.
__global__ __launch_bounds__(512, 3) void attn_kernel(
    const unsigned short* __restrict__ q, const unsigned short* __restrict__ k,
    const float* __restrict__ vw, const int* __restrict__ pr,
    const float* __restrict__ rank_emb, const float* __restrict__ rank_w,
    const float* __restrict__ bs, float* __restrict__ out) {
    const int g = blockIdx.x;
    const int b = g & 7, rblk = g >> 3;
    const int tid = threadIdx.x, wave = tid >> 6, lane = tid & 63;
    const int quad = lane >> 4, l16 = lane & 15;
    const int n0 = rblk * 32;

    __shared__ unsigned short klds[128 * 256];  // 64 KB swizzled K tile
    __shared__ float gtab[NBUCK];
    __shared__ float lL[8][32], wdL[8][32];

    if (tid < NBUCK)  // scale * log2e folded in
        gtab[tid] = 0.0625f * 1.44269504f / (1.f + __expf(-rank_w[0] * rank_emb[tid]));

    const unsigned short* qb = q + (size_t)b * N_ * DOUT_;
    const unsigned short* kb = k + (size_t)b * N_ * DOUT_;
    const float* vwb = vw + b * N_;
    const int* prb = pr + b * N_;

    short8 qf[2][8];
#pragma unroll
    for (int a = 0; a < 2; ++a)
#pragma unroll
        for (int c = 0; c < 8; ++c)
            qf[a][c] = *(const short8*)(qb + (size_t)(n0 + a * 16 + l16) * DOUT_ + c * 32 + quad * 8);

    float prn[2][4];
#pragma unroll
    for (int a = 0; a < 2; ++a)
#pragma unroll
        for (int r = 0; r < 4; ++r) prn[a][r] = (float)prb[n0 + a * 16 + quad * 4 + r];

    float lacc[2][4], wacc[2][4];
#pragma unroll
    for (int a = 0; a < 2; ++a)
#pragma unroll
        for (int r = 0; r < 4; ++r) { lacc[a][r] = 0.f; wacc[a][r] = 0.f; }

    // staging geometry: slot = i*512 + tid (16B units); row = slot>>5 within
    // chunk; LDS seg = slot&31; global seg = (slot&31) ^ (row&7).
    const int srow_base = tid >> 5;   // + i*16
    const int sseg = tid & 31;
    unsigned short* ldsbase = &klds[(size_t)(wave << 6) * 8];

#pragma unroll 1
    for (int j = 0; j < 16; ++j) {
        const int m0 = j * 128;
        __syncthreads();  // previous chunk's reads complete before overwrite
#pragma unroll
        for (int i = 0; i < 8; ++i) {
            int row = i * 16 + srow_base;
            int gseg = sseg ^ (row & 7);
            const unsigned short* gp = kb + (size_t)(m0 + row) * DOUT_ + gseg * 8;
            load_lds16(gp, ldsbase + (size_t)i * 512 * 8);
        }
        int colw = m0 + wave * 16 + l16;
        float prm = (float)prb[colw];   // overlaps with DMA
        float vwv = vwb[colw];
        __syncthreads();  // drain DMA

        floatx4 s[2];
        s[0] = (floatx4){0.f, 0.f, 0.f, 0.f};
        s[1] = (floatx4){0.f, 0.f, 0.f, 0.f};
        const int trow = wave * 16 + l16;      // col within chunk
        const int sw = l16 & 7;
#pragma unroll
        for (int c = 0; c < 8; ++c) {
            int seg = (quad + 4 * c) ^ sw;
            short8 kf = *(const short8*)&klds[((size_t)trow * 32 + seg) * 8];
            s[0] = __builtin_amdgcn_mfma_f32_16x16x32_bf16(qf[0][c], kf, s[0], 0, 0, 0);
            s[1] = __builtin_amdgcn_mfma_f32_16x16x32_bf16(qf[1][c], kf, s[1], 0, 0, 0);
        }
#pragma unroll
        for (int a = 0; a < 2; ++a)
#pragma unroll
            for (int r = 0; r < 4; ++r) {
                float d5 = fabsf(prn[a][r] - prm) * 0.2f;
                int idx = (int)fminf(d5, 19.0f);
                float p = exp2f(s[a][r] * gtab[idx]);
                lacc[a][r] += p;
                wacc[a][r] += p * vwv;
            }
    }

    // merge partial (l, wd) across the 16 column-lanes
#pragma unroll
    for (int off = 1; off < 16; off <<= 1) {
#pragma unroll
        for (int a = 0; a < 2; ++a)
#pragma unroll
            for (int r = 0; r < 4; ++r) {
                lacc[a][r] += __shfl_xor(lacc[a][r], off, 64);
                wacc[a][r] += __shfl_xor(wacc[a][r], off, 64);
            }
    }
    if (l16 == 0) {
#pragma unroll
        for (int a = 0; a < 2; ++a)
#pragma unroll
            for (int r = 0; r < 4; ++r) {
                int row = a * 16 + quad * 4 + r;
                lL[wave][row]  = lacc[a][r];
                wdL[wave][row] = wacc[a][r];
            }
    }
    __syncthreads();
    if (tid < 32) {
        float l = 0.f, wd = 0.f;
#pragma unroll
        for (int s2 = 0; s2 < 8; ++s2) { l += lL[s2][tid]; wd += wdL[s2][tid]; }
        float logit = wd / l + bs[0];   // bvs already inside vw
        out[(size_t)b * N_ + n0 + tid] = 1.f / (1.f + __expf(-logit));
    }
}

// ---------------- launch ----------------
extern "C" void kernel_launch(void* const* d_in, const int* in_sizes, int n_in,
                              void* d_out, int out_size, void* d_ws, size_t ws_size,
                              hipStream_t stream) {
    const float* x   = (const float*)d_in[0];
    const int*   pr  = (const int*)d_in[1];
    const float* Wq  = (const float*)d_in[2];
    const float* bq  = (const float*)d_in[3];
    const float* Wk  = (const float*)d_in[4];
    const float* bk  = (const float*)d_in[5];
    const float* Wv  = (const float*)d_in[6];
    const float* bv  = (const float*)d_in[7];
    const float* Ws  = (const float*)d_in[8];
    const float* bs  = (const float*)d_in[9];
    const float* remb = (const float*)d_in[10];
    const float* rw   = (const float*)d_in[11];
    float* out = (float*)d_out;

    char* ws = (char*)d_ws;
    unsigned short* xb  = (unsigned short*)ws;                    // 16,777,216 B
    unsigned short* wb  = (unsigned short*)(ws + 16777216);       //    524,288 B
    unsigned short* q   = (unsigned short*)(ws + 17301504);       //  8,388,608 B
    unsigned short* kk  = (unsigned short*)(ws + 25690112);       //  8,388,608 B
    float*          vwp = (float*)(ws + 34078720);                //     65,536 B
    float*          wvs = (float*)(ws + 34144256);                //      2,048 B
    float*          bvs = (float*)(ws + 34146304);                //          4 B

    hipLaunchKernelGGL(prep_kernel, dim3(132), dim3(256), 0, stream,
                       Wq, Wk, Wv, Ws, bv, wb, wvs, bvs);
    hipLaunchKernelGGL(cvt_x_kernel, dim3(4096), dim3(256), 0, stream, x, wvs, bvs, xb, vwp);
    hipLaunchKernelGGL(qkv_kernel, dim3(1024), dim3(256), 0, stream,
                       xb, wb, bq, bk, q, kk);
    hipLaunchKernelGGL(attn_kernel, dim3(512), dim3(512), 0, stream,
                       q, kk, vwp, pr, remb, rw, bs, out);
}

// Round 10
// 182.923 us; speedup vs baseline: 1.6909x; 1.1607x over previous
//
#include <hip/hip_runtime.h>
#include <hip/hip_bf16.h>

#define B_    8
#define N_    2048
#define DIN_  512
#define DOUT_ 256
#define NBUCK 20

typedef __attribute__((ext_vector_type(8))) short  short8;
typedef __attribute__((ext_vector_type(4))) float  floatx4;

__device__ __forceinline__ unsigned short f2b(float f) {
    __hip_bfloat16 h = __float2bfloat16(f);
    unsigned short u;
    __builtin_memcpy(&u, &h, 2);
    return u;
}

__device__ __forceinline__ void load_lds16(const unsigned short* g, unsigned short* l) {
    __builtin_amdgcn_global_load_lds(
        (const __attribute__((address_space(1))) unsigned int*)g,
        (__attribute__((address_space(3))) unsigned int*)l, 16, 0, 0);
}

// ---------------- fused prep: Wq,Wk -> bf16  +  wvs = Wv^T.Ws, bvs = bv.Ws ----
__global__ __launch_bounds__(256) void prep_kernel(
    const float* __restrict__ wq, const float* __restrict__ wk,
    const float* __restrict__ Wv, const float* __restrict__ Ws,
    const float* __restrict__ bv,
    unsigned short* __restrict__ dst, float* __restrict__ wvs,
    float* __restrict__ bvs) {
    const int blk = blockIdx.x, tid = threadIdx.x;
    if (blk < 128) {
        int i = (blk * 256 + tid) * 8;  // 0 .. 262144-8
        const float* src = (i < 131072) ? (wq + i) : (wk + (i - 131072));
        float4 a = *(const float4*)(src);
        float4 b = *(const float4*)(src + 4);
        uint4 r;
        r.x = f2b(a.x) | ((unsigned)f2b(a.y) << 16);
        r.y = f2b(a.z) | ((unsigned)f2b(a.w) << 16);
        r.z = f2b(b.x) | ((unsigned)f2b(b.y) << 16);
        r.w = f2b(b.z) | ((unsigned)f2b(b.w) << 16);
        *(uint4*)(dst + i) = r;
    } else {
        __shared__ float wsl[DOUT_];
        wsl[tid] = Ws[tid];
        __syncthreads();
        if (tid < 128) {
            int d = (blk - 128) * 128 + tid;
            float s = 0.f;
#pragma unroll 8
            for (int o = 0; o < DOUT_; ++o) s += Wv[(size_t)o * DIN_ + d] * wsl[o];
            wvs[d] = s;
        }
        if (blk == 128 && tid < 64) {
            float bb = wsl[tid] * bv[tid] + wsl[tid + 64] * bv[tid + 64] +
                       wsl[tid + 128] * bv[tid + 128] + wsl[tid + 192] * bv[tid + 192];
            for (int off = 1; off < 64; off <<= 1) bb += __shfl_xor(bb, off, 64);
            if (tid == 0) *bvs = bb;
        }
    }
}

// ---------------- x -> bf16, fused vw = x . wvs + bvs ----------------
__global__ __launch_bounds__(256) void cvt_x_kernel(const float* __restrict__ x,
                                                    const float* __restrict__ wvs,
                                                    const float* __restrict__ bvs,
                                                    unsigned short* __restrict__ xb,
                                                    float* __restrict__ vw) {
    int tid = threadIdx.x, wave = tid >> 6, lane = tid & 63;
    int row = blockIdx.x * 4 + wave;
    size_t base = (size_t)row * DIN_ + lane * 8;
    float4 a = *(const float4*)(x + base);
    float4 b = *(const float4*)(x + base + 4);
    float4 wa = *(const float4*)(wvs + lane * 8);
    float4 wb = *(const float4*)(wvs + lane * 8 + 4);
    uint4 r;
    r.x = f2b(a.x) | ((unsigned)f2b(a.y) << 16);
    r.y = f2b(a.z) | ((unsigned)f2b(a.w) << 16);
    r.z = f2b(b.x) | ((unsigned)f2b(b.y) << 16);
    r.w = f2b(b.z) | ((unsigned)f2b(b.w) << 16);
    *(uint4*)(xb + base) = r;
    float d = a.x * wa.x + a.y * wa.y + a.z * wa.z + a.w * wa.w +
              b.x * wb.x + b.y * wb.y + b.z * wb.z + b.w * wb.w;
    for (int off = 1; off < 64; off <<= 1) d += __shfl_xor(d, off, 64);
    if (lane == 0) vw[row] = d + *bvs;  // bvs folded in HERE (only here)
}

// ---------------- Q,K GEMM — m97-style 128x128 LDS-staged tiles --------------
// grid 512 flattened, XCD-swizzled: xcd=g&7, colBlk=(g>>3)&3, rowGrp=g>>5,
// rowBlk=rowGrp*8+xcd -> per XCD a 2MB A-stripe + full 512KB B stay L2-hot.
// 256 threads = 4 waves in 2x2; each wave owns a 64x64 tile = 4x4 accs.
// K-loop: 16 iters of BK=32; stage A/B 128x32 (8KB each) via global_load_lds
// w16 (4 per thread), two barriers per iter (m97 structure), then
// 8 ds_read_b128 + 16 MFMA per wave per iter (m97's exact hot-loop mix).
// Fragment-read bank distribution is uniform (8 lanes per 4-bank group =
// the b128 floor). Replaces the direct-load qkv (~70 TF, exposed L2 latency).
__global__ __launch_bounds__(256, 2) void qkv_kernel(
    const unsigned short* __restrict__ xb, const unsigned short* __restrict__ wb,
    const float* __restrict__ bq, const float* __restrict__ bk,
    unsigned short* __restrict__ qo, unsigned short* __restrict__ ko) {
    __shared__ unsigned short alds[128 * 32];  // 8 KB
    __shared__ unsigned short blds[128 * 32];  // 8 KB
    const int g = blockIdx.x;
    const int xcd = g & 7, t2 = g >> 3;
    const int colBlk = t2 & 3, rowGrp = t2 >> 2;
    const int rowBlk = rowGrp * 8 + xcd;
    const int tid = threadIdx.x;
    const int wave = tid >> 6, lane = tid & 63, quad = lane >> 4, l16 = lane & 15;
    const int wr = wave >> 1, wc = wave & 1;
    const int row0 = rowBlk * 128, col0 = colBlk * 128;

    floatx4 acc[4][4];
#pragma unroll
    for (int i = 0; i < 4; ++i)
#pragma unroll
        for (int j = 0; j < 4; ++j) acc[i][j] = (floatx4){0.f, 0.f, 0.f, 0.f};

    // staging: slot = i*256 + tid; row = slot>>2, seg = slot&3 (16B units)
    const unsigned short* ag = xb + (size_t)(row0 + (tid >> 2)) * DIN_ + (tid & 3) * 8;
    const unsigned short* bg = wb + (size_t)(col0 + (tid >> 2)) * DIN_ + (tid & 3) * 8;
    unsigned short* alw0 = alds + (size_t)(wave * 64) * 8;
    unsigned short* alw1 = alds + (size_t)(256 + wave * 64) * 8;
    unsigned short* blw0 = blds + (size_t)(wave * 64) * 8;
    unsigned short* blw1 = blds + (size_t)(256 + wave * 64) * 8;

#pragma unroll 1
    for (int kc = 0; kc < DIN_; kc += 32) {
        __syncthreads();  // previous iteration's reads complete
        load_lds16(ag + kc, alw0);
        load_lds16(ag + (size_t)64 * DIN_ + kc, alw1);
        load_lds16(bg + kc, blw0);
        load_lds16(bg + (size_t)64 * DIN_ + kc, blw1);
        __syncthreads();  // drain DMA
        short8 af[4], bf[4];
#pragma unroll
        for (int f = 0; f < 4; ++f) {
            af[f] = *(const short8*)&alds[(size_t)(wr * 64 + f * 16 + l16) * 32 + quad * 8];
            bf[f] = *(const short8*)&blds[(size_t)(wc * 64 + f * 16 + l16) * 32 + quad * 8];
        }
#pragma unroll
        for (int i = 0; i < 4; ++i)
#pragma unroll
            for (int j = 0; j < 4; ++j)
                acc[i][j] = __builtin_amdgcn_mfma_f32_16x16x32_bf16(af[i], bf[j], acc[i][j], 0, 0, 0);
    }

    // epilogue: bias + bf16 store (C layout: col=l16, row=quad*4+r)
#pragma unroll
    for (int j = 0; j < 4; ++j) {
        int col = col0 + wc * 64 + j * 16 + l16;
        unsigned short* dst = (col < 256) ? qo : ko;
        float bias = (col < 256) ? bq[col] : bk[col - 256];
        int c = col & 255;
#pragma unroll
        for (int i = 0; i < 4; ++i)
#pragma unroll
            for (int r = 0; r < 4; ++r) {
                int row = row0 + wr * 64 + i * 16 + quad * 4 + r;
                dst[(size_t)row * DOUT_ + c] = f2b(acc[i][j][r] + bias);
            }
    }
}

// ---------------- gated flash attention, LDS-staged K (unchanged from r9) ----
__global__ __launch_bounds__(512, 3) void attn_kernel(
    const unsigned short* __restrict__ q, const unsigned short* __restrict__ k,
    const float* __restrict__ vw, const int* __restrict__ pr,
    const float* __restrict__ rank_emb, const float* __restrict__ rank_w,
    const float* __restrict__ bs, float* __restrict__ out) {
    const int g = blockIdx.x;
    const int b = g & 7, rblk = g >> 3;
    const int tid = threadIdx.x, wave = tid >> 6, lane = tid & 63;
    const int quad = lane >> 4, l16 = lane & 15;
    const int n0 = rblk * 32;

    __shared__ unsigned short klds[128 * 256];  // 64 KB swizzled K tile
    __shared__ float gtab[NBUCK];
    __shared__ float lL[8][32], wdL[8][32];

    if (tid < NBUCK)  // scale * log2e folded in
        gtab[tid] = 0.0625f * 1.44269504f / (1.f + __expf(-rank_w[0] * rank_emb[tid]));

    const unsigned short* qb = q + (size_t)b * N_ * DOUT_;
    const unsigned short* kb = k + (size_t)b * N_ * DOUT_;
    const float* vwb = vw + b * N_;
    const int* prb = pr + b * N_;

    short8 qf[2][8];
#pragma unroll
    for (int a = 0; a < 2; ++a)
#pragma unroll
        for (int c = 0; c < 8; ++c)
            qf[a][c] = *(const short8*)(qb + (size_t)(n0 + a * 16 + l16) * DOUT_ + c * 32 + quad * 8);

    float prn[2][4];
#pragma unroll
    for (int a = 0; a < 2; ++a)
#pragma unroll
        for (int r = 0; r < 4; ++r) prn[a][r] = (float)prb[n0 + a * 16 + quad * 4 + r];

    float lacc[2][4], wacc[2][4];
#pragma unroll
    for (int a = 0; a < 2; ++a)
#pragma unroll
        for (int r = 0; r < 4; ++r) { lacc[a][r] = 0.f; wacc[a][r] = 0.f; }

    const int srow_base = tid >> 5;
    const int sseg = tid & 31;
    unsigned short* ldsbase = &klds[(size_t)(wave << 6) * 8];

#pragma unroll 1
    for (int j = 0; j < 16; ++j) {
        const int m0 = j * 128;
        __syncthreads();
#pragma unroll
        for (int i = 0; i < 8; ++i) {
            int row = i * 16 + srow_base;
            int gseg = sseg ^ (row & 7);
            const unsigned short* gp = kb + (size_t)(m0 + row) * DOUT_ + gseg * 8;
            load_lds16(gp, ldsbase + (size_t)i * 512 * 8);
        }
        int colw = m0 + wave * 16 + l16;
        float prm = (float)prb[colw];
        float vwv = vwb[colw];
        __syncthreads();

        floatx4 s[2];
        s[0] = (floatx4){0.f, 0.f, 0.f, 0.f};
        s[1] = (floatx4){0.f, 0.f, 0.f, 0.f};
        const int trow = wave * 16 + l16;
        const int sw = l16 & 7;
#pragma unroll
        for (int c = 0; c < 8; ++c) {
            int seg = (quad + 4 * c) ^ sw;
            short8 kf = *(const short8*)&klds[((size_t)trow * 32 + seg) * 8];
            s[0] = __builtin_amdgcn_mfma_f32_16x16x32_bf16(qf[0][c], kf, s[0], 0, 0, 0);
            s[1] = __builtin_amdgcn_mfma_f32_16x16x32_bf16(qf[1][c], kf, s[1], 0, 0, 0);
        }
#pragma unroll
        for (int a = 0; a < 2; ++a)
#pragma unroll
            for (int r = 0; r < 4; ++r) {
                float d5 = fabsf(prn[a][r] - prm) * 0.2f;
                int idx = (int)fminf(d5, 19.0f);
                float p = exp2f(s[a][r] * gtab[idx]);
                lacc[a][r] += p;
                wacc[a][r] += p * vwv;
            }
    }

#pragma unroll
    for (int off = 1; off < 16; off <<= 1) {
#pragma unroll
        for (int a = 0; a < 2; ++a)
#pragma unroll
            for (int r = 0; r < 4; ++r) {
                lacc[a][r] += __shfl_xor(lacc[a][r], off, 64);
                wacc[a][r] += __shfl_xor(wacc[a][r], off, 64);
            }
    }
    if (l16 == 0) {
#pragma unroll
        for (int a = 0; a < 2; ++a)
#pragma unroll
            for (int r = 0; r < 4; ++r) {
                int row = a * 16 + quad * 4 + r;
                lL[wave][row]  = lacc[a][r];
                wdL[wave][row] = wacc[a][r];
            }
    }
    __syncthreads();
    if (tid < 32) {
        float l = 0.f, wd = 0.f;
#pragma unroll
        for (int s2 = 0; s2 < 8; ++s2) { l += lL[s2][tid]; wd += wdL[s2][tid]; }
        float logit = wd / l + bs[0];   // bvs already inside vw
        out[(size_t)b * N_ + n0 + tid] = 1.f / (1.f + __expf(-logit));
    }
}

// ---------------- launch ----------------
extern "C" void kernel_launch(void* const* d_in, const int* in_sizes, int n_in,
                              void* d_out, int out_size, void* d_ws, size_t ws_size,
                              hipStream_t stream) {
    const float* x   = (const float*)d_in[0];
    const int*   pr  = (const int*)d_in[1];
    const float* Wq  = (const float*)d_in[2];
    const float* bq  = (const float*)d_in[3];
    const float* Wk  = (const float*)d_in[4];
    const float* bk  = (const float*)d_in[5];
    const float* Wv  = (const float*)d_in[6];
    const float* bv  = (const float*)d_in[7];
    const float* Ws  = (const float*)d_in[8];
    const float* bs  = (const float*)d_in[9];
    const float* remb = (const float*)d_in[10];
    const float* rw   = (const float*)d_in[11];
    float* out = (float*)d_out;

    char* ws = (char*)d_ws;
    unsigned short* xb  = (unsigned short*)ws;                    // 16,777,216 B
    unsigned short* wb  = (unsigned short*)(ws + 16777216);       //    524,288 B
    unsigned short* q   = (unsigned short*)(ws + 17301504);       //  8,388,608 B
    unsigned short* kk  = (unsigned short*)(ws + 25690112);       //  8,388,608 B
    float*          vwp = (float*)(ws + 34078720);                //     65,536 B
    float*          wvs = (float*)(ws + 34144256);                //      2,048 B
    float*          bvs = (float*)(ws + 34146304);                //          4 B

    hipLaunchKernelGGL(prep_kernel, dim3(132), dim3(256), 0, stream,
                       Wq, Wk, Wv, Ws, bv, wb, wvs, bvs);
    hipLaunchKernelGGL(cvt_x_kernel, dim3(4096), dim3(256), 0, stream, x, wvs, bvs, xb, vwp);
    hipLaunchKernelGGL(qkv_kernel, dim3(512), dim3(256), 0, stream,
                       xb, wb, bq, bk, q, kk);
    hipLaunchKernelGGL(attn_kernel, dim3(512), dim3(512), 0, stream,
                       q, kk, vwp, pr, remb, rw, bs, out);
}

// Round 11
// 159.889 us; speedup vs baseline: 1.9345x; 1.1441x over previous
//
#include <hip/hip_runtime.h>
#include <hip/hip_bf16.h>

#define B_    8
#define N_    2048
#define DIN_  512
#define DOUT_ 256
#define NBUCK 20

typedef __attribute__((ext_vector_type(8))) short  short8;
typedef __attribute__((ext_vector_type(4))) float  floatx4;

__device__ __forceinline__ unsigned short f2b(float f) {
    __hip_bfloat16 h = __float2bfloat16(f);
    unsigned short u;
    __builtin_memcpy(&u, &h, 2);
    return u;
}

__device__ __forceinline__ void load_lds16(const unsigned short* g, unsigned short* l) {
    __builtin_amdgcn_global_load_lds(
        (const __attribute__((address_space(1))) unsigned int*)g,
        (__attribute__((address_space(3))) unsigned int*)l, 16, 0, 0);
}

// ---------------- fused prep: Wq,Wk -> bf16  +  wvs = Wv^T.Ws, bvs = bv.Ws ----
__global__ __launch_bounds__(256) void prep_kernel(
    const float* __restrict__ wq, const float* __restrict__ wk,
    const float* __restrict__ Wv, const float* __restrict__ Ws,
    const float* __restrict__ bv,
    unsigned short* __restrict__ dst, float* __restrict__ wvs,
    float* __restrict__ bvs) {
    const int blk = blockIdx.x, tid = threadIdx.x;
    if (blk < 128) {
        int i = (blk * 256 + tid) * 8;  // 0 .. 262144-8
        const float* src = (i < 131072) ? (wq + i) : (wk + (i - 131072));
        float4 a = *(const float4*)(src);
        float4 b = *(const float4*)(src + 4);
        uint4 r;
        r.x = f2b(a.x) | ((unsigned)f2b(a.y) << 16);
        r.y = f2b(a.z) | ((unsigned)f2b(a.w) << 16);
        r.z = f2b(b.x) | ((unsigned)f2b(b.y) << 16);
        r.w = f2b(b.z) | ((unsigned)f2b(b.w) << 16);
        *(uint4*)(dst + i) = r;
    } else {
        __shared__ float wsl[DOUT_];
        wsl[tid] = Ws[tid];
        __syncthreads();
        if (tid < 128) {
            int d = (blk - 128) * 128 + tid;
            float s = 0.f;
#pragma unroll 8
            for (int o = 0; o < DOUT_; ++o) s += Wv[(size_t)o * DIN_ + d] * wsl[o];
            wvs[d] = s;
        }
        if (blk == 128 && tid < 64) {
            float bb = wsl[tid] * bv[tid] + wsl[tid + 64] * bv[tid + 64] +
                       wsl[tid + 128] * bv[tid + 128] + wsl[tid + 192] * bv[tid + 192];
            for (int off = 1; off < 64; off <<= 1) bb += __shfl_xor(bb, off, 64);
            if (tid == 0) *bvs = bb;
        }
    }
}

// ---------------- x -> bf16, fused vw = x . wvs + bvs ----------------
__global__ __launch_bounds__(256) void cvt_x_kernel(const float* __restrict__ x,
                                                    const float* __restrict__ wvs,
                                                    const float* __restrict__ bvs,
                                                    unsigned short* __restrict__ xb,
                                                    float* __restrict__ vw) {
    int tid = threadIdx.x, wave = tid >> 6, lane = tid & 63;
    int row = blockIdx.x * 4 + wave;
    size_t base = (size_t)row * DIN_ + lane * 8;
    float4 a = *(const float4*)(x + base);
    float4 b = *(const float4*)(x + base + 4);
    float4 wa = *(const float4*)(wvs + lane * 8);
    float4 wb = *(const float4*)(wvs + lane * 8 + 4);
    uint4 r;
    r.x = f2b(a.x) | ((unsigned)f2b(a.y) << 16);
    r.y = f2b(a.z) | ((unsigned)f2b(a.w) << 16);
    r.z = f2b(b.x) | ((unsigned)f2b(b.y) << 16);
    r.w = f2b(b.z) | ((unsigned)f2b(b.w) << 16);
    *(uint4*)(xb + base) = r;
    float d = a.x * wa.x + a.y * wa.y + a.z * wa.z + a.w * wa.w +
              b.x * wb.x + b.y * wb.y + b.z * wb.z + b.w * wb.w;
    for (int off = 1; off < 64; off <<= 1) d += __shfl_xor(d, off, 64);
    if (lane == 0) vw[row] = d + *bvs;  // bvs folded in HERE (only here)
}

// ---------------- Q,K GEMM — m97-style 128x128 LDS-staged tiles (r10) --------
__global__ __launch_bounds__(256, 2) void qkv_kernel(
    const unsigned short* __restrict__ xb, const unsigned short* __restrict__ wb,
    const float* __restrict__ bq, const float* __restrict__ bk,
    unsigned short* __restrict__ qo, unsigned short* __restrict__ ko) {
    __shared__ unsigned short alds[128 * 32];  // 8 KB
    __shared__ unsigned short blds[128 * 32];  // 8 KB
    const int g = blockIdx.x;
    const int xcd = g & 7, t2 = g >> 3;
    const int colBlk = t2 & 3, rowGrp = t2 >> 2;
    const int rowBlk = rowGrp * 8 + xcd;
    const int tid = threadIdx.x;
    const int wave = tid >> 6, lane = tid & 63, quad = lane >> 4, l16 = lane & 15;
    const int wr = wave >> 1, wc = wave & 1;
    const int row0 = rowBlk * 128, col0 = colBlk * 128;

    floatx4 acc[4][4];
#pragma unroll
    for (int i = 0; i < 4; ++i)
#pragma unroll
        for (int j = 0; j < 4; ++j) acc[i][j] = (floatx4){0.f, 0.f, 0.f, 0.f};

    const unsigned short* ag = xb + (size_t)(row0 + (tid >> 2)) * DIN_ + (tid & 3) * 8;
    const unsigned short* bg = wb + (size_t)(col0 + (tid >> 2)) * DIN_ + (tid & 3) * 8;
    unsigned short* alw0 = alds + (size_t)(wave * 64) * 8;
    unsigned short* alw1 = alds + (size_t)(256 + wave * 64) * 8;
    unsigned short* blw0 = blds + (size_t)(wave * 64) * 8;
    unsigned short* blw1 = blds + (size_t)(256 + wave * 64) * 8;

#pragma unroll 1
    for (int kc = 0; kc < DIN_; kc += 32) {
        __syncthreads();
        load_lds16(ag + kc, alw0);
        load_lds16(ag + (size_t)64 * DIN_ + kc, alw1);
        load_lds16(bg + kc, blw0);
        load_lds16(bg + (size_t)64 * DIN_ + kc, blw1);
        __syncthreads();
        short8 af[4], bf[4];
#pragma unroll
        for (int f = 0; f < 4; ++f) {
            af[f] = *(const short8*)&alds[(size_t)(wr * 64 + f * 16 + l16) * 32 + quad * 8];
            bf[f] = *(const short8*)&blds[(size_t)(wc * 64 + f * 16 + l16) * 32 + quad * 8];
        }
#pragma unroll
        for (int i = 0; i < 4; ++i)
#pragma unroll
            for (int j = 0; j < 4; ++j)
                acc[i][j] = __builtin_amdgcn_mfma_f32_16x16x32_bf16(af[i], bf[j], acc[i][j], 0, 0, 0);
    }

#pragma unroll
    for (int j = 0; j < 4; ++j) {
        int col = col0 + wc * 64 + j * 16 + l16;
        unsigned short* dst = (col < 256) ? qo : ko;
        float bias = (col < 256) ? bq[col] : bk[col - 256];
        int c = col & 255;
#pragma unroll
        for (int i = 0; i < 4; ++i)
#pragma unroll
            for (int r = 0; r < 4; ++r) {
                int row = row0 + wr * 64 + i * 16 + quad * 4 + r;
                dst[(size_t)row * DOUT_ + c] = f2b(acc[i][j][r] + bias);
            }
    }
}

// ---------------- gated flash attention — barrier-free per-wave pipeline -----
// grid 256: b = g&7 (XCD-affine), rblk = g>>3 -> 64 q-rows/block, 8 waves.
// Each wave owns 16 K-cols per 128-col chunk and stages ONLY those into a
// PRIVATE double-buffered 8KB LDS region (2x8 waves x 8KB = 128KB) via
// global_load_lds w16. Zero cross-wave sharing -> NO barriers in the chunk
// loop: per-wave vmcnt ordering (compiler-inserted) is the only sync, so
// chunk j+1's DMA overlaps chunk j's MFMA+exp — the m97 barrier-drain
// plateau (r9/r10's residual ~60%) is structurally removed.
// 64 q-rows: qf[4][8] (128 VGPRs), each kf feeds 4 MFMAs; per-CU staged
// traffic halves vs r10. kf kept scalar in the c-loop (r5 spill lesson).
__global__ __launch_bounds__(512, 2) void attn_kernel(
    const unsigned short* __restrict__ q, const unsigned short* __restrict__ k,
    const float* __restrict__ vw, const int* __restrict__ pr,
    const float* __restrict__ rank_emb, const float* __restrict__ rank_w,
    const float* __restrict__ bs, float* __restrict__ out) {
    const int g = blockIdx.x;
    const int b = g & 7, rblk = g >> 3;
    const int tid = threadIdx.x, wave = tid >> 6, lane = tid & 63;
    const int quad = lane >> 4, l16 = lane & 15;
    const int n0 = rblk * 64;
    const int sw = l16 & 7;

    __shared__ unsigned short klds[2][8][4096];  // [parity][wave][8KB]
    __shared__ float gtab[NBUCK];
    __shared__ float lL[8][64], wdL[8][64];

    if (tid < NBUCK)  // scale * log2e folded in
        gtab[tid] = 0.0625f * 1.44269504f / (1.f + __expf(-rank_w[0] * rank_emb[tid]));
    __syncthreads();  // the ONLY pre-loop barrier (gtab visibility)

    const unsigned short* qb = q + (size_t)b * N_ * DOUT_;
    const unsigned short* kb = k + (size_t)b * N_ * DOUT_;
    const float* vwb = vw + b * N_;
    const int* prb = pr + b * N_;

    short8 qf[4][8];
#pragma unroll
    for (int a = 0; a < 4; ++a)
#pragma unroll
        for (int c = 0; c < 8; ++c)
            qf[a][c] = *(const short8*)(qb + (size_t)(n0 + a * 16 + l16) * DOUT_ + c * 32 + quad * 8);

    float prn[4][4];
#pragma unroll
    for (int a = 0; a < 4; ++a)
#pragma unroll
        for (int r = 0; r < 4; ++r) prn[a][r] = (float)prb[n0 + a * 16 + quad * 4 + r];

    float lacc[4][4], wacc[4][4];
#pragma unroll
    for (int a = 0; a < 4; ++a)
#pragma unroll
        for (int r = 0; r < 4; ++r) { lacc[a][r] = 0.f; wacc[a][r] = 0.f; }

    // per-wave private staging: wave's 16 K-rows x 512B = 8KB = 8 issues/lane.
    // slot = i*64 + lane; local row = slot>>5 = i*2 + (lane>>5); pos = lane&31;
    // global seg = pos ^ (row&7)  (XOR swizzle; LDS dest stays lane-contiguous)
    const int srow = lane >> 5;
    const int spos = lane & 31;
    const unsigned short* kwb = kb + (size_t)(wave * 16) * DOUT_;
    unsigned short* buf0 = &klds[0][wave][0];
    unsigned short* buf1 = &klds[1][wave][0];

    // prologue: stage chunk 0
#pragma unroll
    for (int i = 0; i < 8; ++i) {
        int row = i * 2 + srow;
        int gseg = spos ^ (row & 7);
        load_lds16(kwb + (size_t)row * DOUT_ + gseg * 8, buf0 + i * 512);
    }

#pragma unroll 1
    for (int j = 0; j < 16; ++j) {
        unsigned short* bufc = (j & 1) ? buf1 : buf0;
        unsigned short* bufn = (j & 1) ? buf0 : buf1;

        // ---- fragment reads + MFMA (vmcnt wait on THIS wave's chunk-j DMA) --
        floatx4 s[4];
#pragma unroll
        for (int a = 0; a < 4; ++a) s[a] = (floatx4){0.f, 0.f, 0.f, 0.f};
#pragma unroll
        for (int c = 0; c < 8; ++c) {
            int seg = (quad + 4 * c) ^ sw;
            short8 kf = *(const short8*)&bufc[((size_t)l16 * 32 + seg) * 8];
            s[0] = __builtin_amdgcn_mfma_f32_16x16x32_bf16(qf[0][c], kf, s[0], 0, 0, 0);
            s[1] = __builtin_amdgcn_mfma_f32_16x16x32_bf16(qf[1][c], kf, s[1], 0, 0, 0);
            s[2] = __builtin_amdgcn_mfma_f32_16x16x32_bf16(qf[2][c], kf, s[2], 0, 0, 0);
            s[3] = __builtin_amdgcn_mfma_f32_16x16x32_bf16(qf[3][c], kf, s[3], 0, 0, 0);
        }
        // ---- prefetch chunk j+1 (overlaps exp below + next iter's wait) -----
        if (j < 15) {
            const unsigned short* src = kwb + (size_t)(j + 1) * 128 * DOUT_;
#pragma unroll
            for (int i = 0; i < 8; ++i) {
                int row = i * 2 + srow;
                int gseg = spos ^ (row & 7);
                load_lds16(src + (size_t)row * DOUT_ + gseg * 8, bufn + i * 512);
            }
        }
        int colw = j * 128 + wave * 16 + l16;
        float prm = (float)prb[colw];
        float vwv = vwb[colw];
        // ---- gate + exp accumulation ----------------------------------------
#pragma unroll
        for (int a = 0; a < 4; ++a)
#pragma unroll
            for (int r = 0; r < 4; ++r) {
                float d5 = fabsf(prn[a][r] - prm) * 0.2f;
                int idx = (int)fminf(d5, 19.0f);
                float p = exp2f(s[a][r] * gtab[idx]);
                lacc[a][r] += p;
                wacc[a][r] += p * vwv;
            }
    }

    // merge partial (l, wd) across the 16 column-lanes
#pragma unroll
    for (int off = 1; off < 16; off <<= 1) {
#pragma unroll
        for (int a = 0; a < 4; ++a)
#pragma unroll
            for (int r = 0; r < 4; ++r) {
                lacc[a][r] += __shfl_xor(lacc[a][r], off, 64);
                wacc[a][r] += __shfl_xor(wacc[a][r], off, 64);
            }
    }
    if (l16 == 0) {
#pragma unroll
        for (int a = 0; a < 4; ++a)
#pragma unroll
            for (int r = 0; r < 4; ++r) {
                int row = a * 16 + quad * 4 + r;
                lL[wave][row]  = lacc[a][r];
                wdL[wave][row] = wacc[a][r];
            }
    }
    __syncthreads();
    if (tid < 64) {
        float l = 0.f, wd = 0.f;
#pragma unroll
        for (int s2 = 0; s2 < 8; ++s2) { l += lL[s2][tid]; wd += wdL[s2][tid]; }
        float logit = wd / l + bs[0];   // bvs already inside vw
        out[(size_t)b * N_ + n0 + tid] = 1.f / (1.f + __expf(-logit));
    }
}

// ---------------- launch ----------------
extern "C" void kernel_launch(void* const* d_in, const int* in_sizes, int n_in,
                              void* d_out, int out_size, void* d_ws, size_t ws_size,
                              hipStream_t stream) {
    const float* x   = (const float*)d_in[0];
    const int*   pr  = (const int*)d_in[1];
    const float* Wq  = (const float*)d_in[2];
    const float* bq  = (const float*)d_in[3];
    const float* Wk  = (const float*)d_in[4];
    const float* bk  = (const float*)d_in[5];
    const float* Wv  = (const float*)d_in[6];
    const float* bv  = (const float*)d_in[7];
    const float* Ws  = (const float*)d_in[8];
    const float* bs  = (const float*)d_in[9];
    const float* remb = (const float*)d_in[10];
    const float* rw   = (const float*)d_in[11];
    float* out = (float*)d_out;

    char* ws = (char*)d_ws;
    unsigned short* xb  = (unsigned short*)ws;                    // 16,777,216 B
    unsigned short* wb  = (unsigned short*)(ws + 16777216);       //    524,288 B
    unsigned short* q   = (unsigned short*)(ws + 17301504);       //  8,388,608 B
    unsigned short* kk  = (unsigned short*)(ws + 25690112);       //  8,388,608 B
    float*          vwp = (float*)(ws + 34078720);                //     65,536 B
    float*          wvs = (float*)(ws + 34144256);                //      2,048 B
    float*          bvs = (float*)(ws + 34146304);                //          4 B

    hipLaunchKernelGGL(prep_kernel, dim3(132), dim3(256), 0, stream,
                       Wq, Wk, Wv, Ws, bv, wb, wvs, bvs);
    hipLaunchKernelGGL(cvt_x_kernel, dim3(4096), dim3(256), 0, stream, x, wvs, bvs, xb, vwp);
    hipLaunchKernelGGL(qkv_kernel, dim3(512), dim3(256), 0, stream,
                       xb, wb, bq, bk, q, kk);
    hipLaunchKernelGGL(attn_kernel, dim3(256), dim3(512), 0, stream,
                       q, kk, vwp, pr, remb, rw, bs, out);
}